// Round 5
// baseline (158.604 us; speedup 1.0000x reference)
//
#include <hip/hip_runtime.h>

// DeepDFTinv message block: B=2, P=4096, A=96, G=1, F=32, E=20
#define NB   2
#define NP   4096
#define NA   96
#define NF   32
#define NE   20
#define NBP  (NB*NP)

typedef __attribute__((ext_vector_type(8)))  short bf16x8;   // MFMA A/B frag (4 VGPRs)
typedef __attribute__((ext_vector_type(16))) float f32x16;   // 32x32 MFMA C/D frag

union Frag { bf16x8 v; int i[4]; };

// single-instruction packed f32->bf16 (RNE), src0 -> low half
__device__ __forceinline__ int cvtpk(float lo, float hi) {
  int r;
  asm("v_cvt_pk_bf16_f32 %0, %1, %2" : "=v"(r) : "v"(lo), "v"(hi));
  return r;
}
// shifted softplus: max(x,0) + log(1 + exp(-|x|)) - ln2
__device__ __forceinline__ float ssp_f(float x) {
  float t = __expf(-fabsf(x));
  return fmaxf(x, 0.0f) + __logf(1.0f + t) - 0.69314718056f;
}
__device__ __forceinline__ f32x16 mfma32(const Frag a, const Frag b, f32x16 c) {
  return __builtin_amdgcn_mfma_f32_32x32x16_bf16(a.v, b.v, c, 0, 0, 0);
}
// C-init from 32-float LDS bias vector. rows = (r&3)+8*(r>>2)+4*hw
__device__ __forceinline__ f32x16 ld_bias16(const float* base /* bias + 4*hw */) {
  const float4* p = reinterpret_cast<const float4*>(base);
  float4 q0 = p[0], q1 = p[2], q2 = p[4], q3 = p[6];
  f32x16 c;
  c[0]=q0.x;  c[1]=q0.y;  c[2]=q0.z;  c[3]=q0.w;
  c[4]=q1.x;  c[5]=q1.y;  c[6]=q1.z;  c[7]=q1.w;
  c[8]=q2.x;  c[9]=q2.y;  c[10]=q2.z; c[11]=q2.w;
  c[12]=q3.x; c[13]=q3.y; c[14]=q3.z; c[15]=q3.w;
  return c;
}

// ---------- prep ----------
// blocks [0,1048): tgt = sr @ Wt -> d_out rows; src = scalar @ Ws + b1n -> d_ws
// blocks [1048,1050): pack the 6 transposed bf16 weight A-fragments -> ftab
__global__ __launch_bounds__(256)
void prep_kernel(const float* __restrict__ scalar,
                 const float* __restrict__ sr,
                 const float* __restrict__ W1e,
                 const float* __restrict__ W2e,
                 const float* __restrict__ W2n,
                 const float* __restrict__ W1n,
                 const float* __restrict__ b1n,
                 float* __restrict__ tgt_out,
                 float* __restrict__ src_ws,
                 int4* __restrict__ ftab)
{
  const int blk = blockIdx.x;
  if (blk < 1048) {
    int i = blk * 256 + threadIdx.x;     // 1048*256 = (8192+192)*32 exactly
    int f   = i & 31;
    int row = i >> 5;
    const float* x;
    const float* W;
    float acc;
    if (row < NBP) { x = sr + row * NF;             W = W1n + NF * NF; acc = 0.0f;   }
    else           { x = scalar + (row - NBP) * NF; W = W1n;           acc = b1n[f]; }
    float4 xv[8];
#pragma unroll
    for (int q = 0; q < 8; ++q) xv[q] = reinterpret_cast<const float4*>(x)[q];
#pragma unroll
    for (int q = 0; q < 8; ++q) {
      acc = fmaf(xv[q].x, W[(4 * q + 0) * NF + f], acc);
      acc = fmaf(xv[q].y, W[(4 * q + 1) * NF + f], acc);
      acc = fmaf(xv[q].z, W[(4 * q + 2) * NF + f], acc);
      acc = fmaf(xv[q].w, W[(4 * q + 3) * NF + f], acc);
    }
    if (row < NBP) tgt_out[i] = acc;
    else           src_ws[(row - NBP) * NF + f] = acc;
  } else {
    int e = (blk - 1048) * 256 + threadIdx.x;   // 0..383 valid
    if (e < 384) {
      const int f  = e >> 6;        // frag id: 0..5
      const int l  = e & 63;
      const int c  = l & 31;
      const int hw = l >> 5;
      const float* W = (f < 2) ? W1e : ((f < 4) ? W2e : W2n);
      const int kbase = (f & 1) ? (16 + 8 * hw) : (8 * hw);
      int4 v;
      int* vi = reinterpret_cast<int*>(&v);
#pragma unroll
      for (int r = 0; r < 4; ++r) {
        int ka = kbase + 2 * r, kb = ka + 1;
        bool pa = (f == 1) && (ka >= NE);     // zero-pad e>=20 in W1e^T high-K frag
        bool pb = (f == 1) && (kb >= NE);
        float lo = W[(pa ? 0 : ka) * NF + c]; lo = pa ? 0.0f : lo;
        float hi = W[(pb ? 0 : kb) * NF + c]; hi = pb ? 0.0f : hi;
        vi[r] = cvtpk(lo, hi);
      }
      ftab[e] = v;
    }
  }
}

// ---------- main: 4 waves/block, ONE (b,p) per wave; grid 2048 ----------
__global__ __launch_bounds__(256, 4)
void fused_main(const float* __restrict__ expansion,
                const float* __restrict__ mask,
                const float* __restrict__ edge_dist,
                const float* __restrict__ b1e,
                const float* __restrict__ b2e,
                const float* __restrict__ b2n,
                const float* __restrict__ src_ws,
                const int4* __restrict__ ftab,
                float* __restrict__ out)
{
  const int tid  = threadIdx.x;
  const int wid  = tid >> 6;
  const int lane = tid & 63;
  const int col  = lane & 31;    // matrix column (= a)
  const int hw   = lane >> 5;    // half-wave (k-split)

  __shared__ __align__(16) float smb[96];   // b1e | b2e | b2n
  if (tid < 32) {
    smb[tid]      = b1e[tid];
    smb[32 + tid] = b2e[tid];
    smb[64 + tid] = b2n[tid];
  }
  __syncthreads();
  const float* biasA = smb      + 4 * hw;
  const float* biasB = smb + 32 + 4 * hw;
  const float* biasC = smb + 64 + 4 * hw;

  // ---- pre-packed transposed-weight A-fragments (6 x dwordx4, L2-hot) ----
  Frag a1s0, a1s1, a2s0, a2s1, a3s0, a3s1;
  {
    int4 w0 = ftab[0 * 64 + lane];
    int4 w1 = ftab[1 * 64 + lane];
    int4 w2 = ftab[2 * 64 + lane];
    int4 w3 = ftab[3 * 64 + lane];
    int4 w4 = ftab[4 * 64 + lane];
    int4 w5 = ftab[5 * 64 + lane];
    a1s0.i[0]=w0.x; a1s0.i[1]=w0.y; a1s0.i[2]=w0.z; a1s0.i[3]=w0.w;
    a1s1.i[0]=w1.x; a1s1.i[1]=w1.y; a1s1.i[2]=w1.z; a1s1.i[3]=w1.w;
    a2s0.i[0]=w2.x; a2s0.i[1]=w2.y; a2s0.i[2]=w2.z; a2s0.i[3]=w2.w;
    a2s1.i[0]=w3.x; a2s1.i[1]=w3.y; a2s1.i[2]=w3.z; a2s1.i[3]=w3.w;
    a3s0.i[0]=w4.x; a3s0.i[1]=w4.y; a3s0.i[2]=w4.z; a3s0.i[3]=w4.w;
    a3s1.i[0]=w5.x; a3s1.i[1]=w5.y; a3s1.i[2]=w5.z; a3s1.i[3]=w5.w;
  }

  const int bp = blockIdx.x * 4 + wid;   // grid 2048 -> bp in [0, 8192)
  const int b  = bp >> 12;               // NP = 4096

  // ---- prefetch ALL per-bp HBM streams: tgt, expansion, mask, dist ----
  const float* tg = out + bp * NF;       // written by prep_kernel
  float4 t0 = *reinterpret_cast<const float4*>(tg + 8 * hw);
  float4 t1 = *reinterpret_cast<const float4*>(tg + 8 * hw + 4);
  float4 t2 = *reinterpret_cast<const float4*>(tg + 16 + 8 * hw);
  float4 t3 = *reinterpret_cast<const float4*>(tg + 16 + 8 * hw + 4);

  const float* expb  = expansion + (size_t)bp * (NA * NE);
  const float* maskb = mask      + bp * NA;
  const float* distb = edge_dist + bp * NA;
  const float* srcb  = src_ws    + b * (NA * NF);

  float4 ef[3][3];
  float  mk[3], dd[3];
#pragma unroll
  for (int t = 0; t < 3; ++t) {
    const int a = t * 32 + col;
    const float* ea = expb + a * NE;
    ef[t][0] = *reinterpret_cast<const float4*>(ea + 8 * hw);
    ef[t][1] = *reinterpret_cast<const float4*>(ea + 8 * hw + 4);
    ef[t][2] = *reinterpret_cast<const float4*>(ea + 16);   // e=16..19 (hw0 uses)
    mk[t] = maskb[a];
    dd[t] = distb[a];
  }
  float em[3];
#pragma unroll
  for (int t = 0; t < 3; ++t) {
    const float z = __expf(5.0f * (dd[t] - 3.5f));
    em[t] = mk[t] * __builtin_amdgcn_rcpf(1.0f + z);
  }

  f32x16 acc;
#pragma unroll
  for (int r = 0; r < 16; ++r) acc[r] = 0.0f;

#pragma unroll
  for (int t = 0; t < 3; ++t) {
    const int a = t * 32 + col;

    // ---- B1 = expansion^T fragment (k=e, n=a) from prefetched regs ----
    Frag b1f0, b1f1;
    b1f0.i[0] = cvtpk(ef[t][0].x, ef[t][0].y);
    b1f0.i[1] = cvtpk(ef[t][0].z, ef[t][0].w);
    b1f0.i[2] = cvtpk(ef[t][1].x, ef[t][1].y);
    b1f0.i[3] = cvtpk(ef[t][1].z, ef[t][1].w);
    b1f1.i[0] = hw ? 0 : cvtpk(ef[t][2].x, ef[t][2].y);
    b1f1.i[1] = hw ? 0 : cvtpk(ef[t][2].z, ef[t][2].w);
    b1f1.i[2] = 0;
    b1f1.i[3] = 0;

    // ---- GEMM1: H1^T[j][a] ----
    f32x16 d1 = ld_bias16(biasA);
    d1 = mfma32(a1s0, b1f0, d1);
    d1 = mfma32(a1s1, b1f1, d1);
#pragma unroll
    for (int r = 0; r < 16; ++r) d1[r] = ssp_f(d1[r]);

    // ---- C-layout f32 -> B-layout bf16 (cvt_pk + permlane32_swap) ----
    int u0 = cvtpk(d1[0],  d1[1]);
    int u1 = cvtpk(d1[2],  d1[3]);
    int u2 = cvtpk(d1[4],  d1[5]);
    int u3 = cvtpk(d1[6],  d1[7]);
    int u4 = cvtpk(d1[8],  d1[9]);
    int u5 = cvtpk(d1[10], d1[11]);
    int u6 = cvtpk(d1[12], d1[13]);
    int u7 = cvtpk(d1[14], d1[15]);
    asm("v_permlane32_swap_b32 %0, %1" : "+v"(u0), "+v"(u2));
    asm("v_permlane32_swap_b32 %0, %1" : "+v"(u1), "+v"(u3));
    asm("v_permlane32_swap_b32 %0, %1" : "+v"(u4), "+v"(u6));
    asm("v_permlane32_swap_b32 %0, %1" : "+v"(u5), "+v"(u7));
    Frag b2f0, b2f1;
    b2f0.i[0] = u0; b2f0.i[1] = u1; b2f0.i[2] = u2; b2f0.i[3] = u3;
    b2f1.i[0] = u4; b2f1.i[1] = u5; b2f1.i[2] = u6; b2f1.i[3] = u7;

    // ---- GEMM2: gates^T[f][a] ----
    f32x16 d2 = ld_bias16(biasB);
    d2 = mfma32(a2s0, b2f0, d2);
    d2 = mfma32(a2s1, b2f1, d2);

    // ---- nodes B-fragment: ssp(src[a][fh] + tgt[fh]) (src is L1-hot, 24 KB) ----
    const float* sa = srcb + a * NF;
    float4 s0 = *reinterpret_cast<const float4*>(sa + 8 * hw);
    float4 s1 = *reinterpret_cast<const float4*>(sa + 8 * hw + 4);
    float4 s2 = *reinterpret_cast<const float4*>(sa + 16 + 8 * hw);
    float4 s3 = *reinterpret_cast<const float4*>(sa + 16 + 8 * hw + 4);
    Frag b3f0, b3f1;
    b3f0.i[0] = cvtpk(ssp_f(s0.x + t0.x), ssp_f(s0.y + t0.y));
    b3f0.i[1] = cvtpk(ssp_f(s0.z + t0.z), ssp_f(s0.w + t0.w));
    b3f0.i[2] = cvtpk(ssp_f(s1.x + t1.x), ssp_f(s1.y + t1.y));
    b3f0.i[3] = cvtpk(ssp_f(s1.z + t1.z), ssp_f(s1.w + t1.w));
    b3f1.i[0] = cvtpk(ssp_f(s2.x + t2.x), ssp_f(s2.y + t2.y));
    b3f1.i[1] = cvtpk(ssp_f(s2.z + t2.z), ssp_f(s2.w + t2.w));
    b3f1.i[2] = cvtpk(ssp_f(s3.x + t3.x), ssp_f(s3.y + t3.y));
    b3f1.i[3] = cvtpk(ssp_f(s3.z + t3.z), ssp_f(s3.w + t3.w));

    // ---- GEMM3: nodes^T[fo][a] ----
    f32x16 d3 = ld_bias16(biasC);
    d3 = mfma32(a3s0, b3f0, d3);
    d3 = mfma32(a3s1, b3f1, d3);

    // ---- out += em * gates ⊙ nodes ----
#pragma unroll
    for (int r = 0; r < 16; ++r) acc[r] = fmaf(em[t] * d2[r], d3[r], acc[r]);
  }

  // reduce over columns a (32 lanes within each half-wave)
#pragma unroll
  for (int m = 1; m <= 16; m <<= 1) {
#pragma unroll
    for (int r = 0; r < 16; ++r) acc[r] += __shfl_xor(acc[r], m, 64);
  }

  // rows for reg-quad q: 8q + 4hw + (0..3) -> contiguous float4
  if (col == 0) {
    float4* o = reinterpret_cast<float4*>(out + bp * NF);
#pragma unroll
    for (int q = 0; q < 4; ++q) {
      float4 v;
      v.x = acc[4 * q];     v.y = acc[4 * q + 1];
      v.z = acc[4 * q + 2]; v.w = acc[4 * q + 3];
      o[2 * q + hw] = v;
    }
  }
}

extern "C" void kernel_launch(void* const* d_in, const int* in_sizes, int n_in,
                              void* d_out, int out_size, void* d_ws, size_t ws_size,
                              hipStream_t stream) {
  const float* scalar    = (const float*)d_in[0];
  const float* sreciever = (const float*)d_in[1];
  const float* expansion = (const float*)d_in[2];
  const float* maskp     = (const float*)d_in[3];
  const float* edist     = (const float*)d_in[4];
  const float* W1e       = (const float*)d_in[5];
  const float* b1e       = (const float*)d_in[6];
  const float* W2e       = (const float*)d_in[7];
  const float* b2e       = (const float*)d_in[8];
  const float* W1n       = (const float*)d_in[9];
  const float* b1n       = (const float*)d_in[10];
  const float* W2n       = (const float*)d_in[11];
  const float* b2n       = (const float*)d_in[12];
  float* out    = (float*)d_out;
  float* src_ws = (float*)d_ws;                          // 192*32 f32 = 24576 B
  int4*  ftab   = (int4*)((char*)d_ws + 192 * NF * 4);   // 384 int4 = 6144 B

  prep_kernel<<<1050, 256, 0, stream>>>(scalar, sreciever, W1e, W2e, W2n,
                                        W1n, b1n, out, src_ws, ftab);
  // 2048 blocks * 4 waves * 1 bp = 8192 = NBP
  fused_main<<<NBP / 4, 256, 0, stream>>>(expansion, maskp, edist,
                                          b1e, b2e, b2n, src_ws, ftab, out);
}

// Round 6
// 153.246 us; speedup vs baseline: 1.0350x; 1.0350x over previous
//
#include <hip/hip_runtime.h>

// DeepDFTinv message block: B=2, P=4096, A=96, G=1, F=32, E=20
#define NB   2
#define NP   4096
#define NA   96
#define NF   32
#define NE   20
#define NBP  (NB*NP)

typedef __attribute__((ext_vector_type(8)))  short bf16x8;   // MFMA A/B frag (4 VGPRs)
typedef __attribute__((ext_vector_type(16))) float f32x16;   // 32x32 MFMA C/D frag

union Frag { bf16x8 v; int i[4]; };

// single-instruction packed f32->bf16 (RNE), src0 -> low half
__device__ __forceinline__ int cvtpk(float lo, float hi) {
  int r;
  asm("v_cvt_pk_bf16_f32 %0, %1, %2" : "=v"(r) : "v"(lo), "v"(hi));
  return r;
}
// shifted softplus: max(x,0) + log(1 + exp(-|x|)) - ln2
__device__ __forceinline__ float ssp_f(float x) {
  float t = __expf(-fabsf(x));
  return fmaxf(x, 0.0f) + __logf(1.0f + t) - 0.69314718056f;
}
__device__ __forceinline__ f32x16 mfma32(const Frag a, const Frag b, f32x16 c) {
  return __builtin_amdgcn_mfma_f32_32x32x16_bf16(a.v, b.v, c, 0, 0, 0);
}
// C-init from 32-float LDS bias vector. rows = (r&3)+8*(r>>2)+4*hw
__device__ __forceinline__ f32x16 ld_bias16(const float* base /* bias + 4*hw */) {
  const float4* p = reinterpret_cast<const float4*>(base);
  float4 q0 = p[0], q1 = p[2], q2 = p[4], q3 = p[6];
  f32x16 c;
  c[0]=q0.x;  c[1]=q0.y;  c[2]=q0.z;  c[3]=q0.w;
  c[4]=q1.x;  c[5]=q1.y;  c[6]=q1.z;  c[7]=q1.w;
  c[8]=q2.x;  c[9]=q2.y;  c[10]=q2.z; c[11]=q2.w;
  c[12]=q3.x; c[13]=q3.y; c[14]=q3.z; c[15]=q3.w;
  return c;
}

// ---------- prep ----------
// blocks [0,1048): tgt = sr @ Wt -> tgt_ws; src = scalar @ Ws + b1n -> src_ws
// blocks [1048,1050): pack the 6 transposed bf16 weight A-fragments -> ftab
__global__ __launch_bounds__(256)
void prep_kernel(const float* __restrict__ scalar,
                 const float* __restrict__ sr,
                 const float* __restrict__ W1e,
                 const float* __restrict__ W2e,
                 const float* __restrict__ W2n,
                 const float* __restrict__ W1n,
                 const float* __restrict__ b1n,
                 float* __restrict__ tgt_ws,
                 float* __restrict__ src_ws,
                 int4* __restrict__ ftab)
{
  const int blk = blockIdx.x;
  if (blk < 1048) {
    int i = blk * 256 + threadIdx.x;     // 1048*256 = (8192+192)*32 exactly
    int f   = i & 31;
    int row = i >> 5;
    const float* x;
    const float* W;
    float acc;
    if (row < NBP) { x = sr + row * NF;             W = W1n + NF * NF; acc = 0.0f;   }
    else           { x = scalar + (row - NBP) * NF; W = W1n;           acc = b1n[f]; }
    float4 xv[8];
#pragma unroll
    for (int q = 0; q < 8; ++q) xv[q] = reinterpret_cast<const float4*>(x)[q];
#pragma unroll
    for (int q = 0; q < 8; ++q) {
      acc = fmaf(xv[q].x, W[(4 * q + 0) * NF + f], acc);
      acc = fmaf(xv[q].y, W[(4 * q + 1) * NF + f], acc);
      acc = fmaf(xv[q].z, W[(4 * q + 2) * NF + f], acc);
      acc = fmaf(xv[q].w, W[(4 * q + 3) * NF + f], acc);
    }
    if (row < NBP) tgt_ws[i] = acc;
    else           src_ws[(row - NBP) * NF + f] = acc;
  } else {
    int e = (blk - 1048) * 256 + threadIdx.x;   // 0..383 valid
    if (e < 384) {
      const int f  = e >> 6;        // frag id: 0..5
      const int l  = e & 63;
      const int c  = l & 31;
      const int hw = l >> 5;
      const float* W = (f < 2) ? W1e : ((f < 4) ? W2e : W2n);
      const int kbase = (f & 1) ? (16 + 8 * hw) : (8 * hw);
      int4 v;
      int* vi = reinterpret_cast<int*>(&v);
#pragma unroll
      for (int r = 0; r < 4; ++r) {
        int ka = kbase + 2 * r, kb = ka + 1;
        bool pa = (f == 1) && (ka >= NE);     // zero-pad e>=20 in W1e^T high-K frag
        bool pb = (f == 1) && (kb >= NE);
        float lo = W[(pa ? 0 : ka) * NF + c]; lo = pa ? 0.0f : lo;
        float hi = W[(pb ? 0 : kb) * NF + c]; hi = pb ? 0.0f : hi;
        vi[r] = cvtpk(lo, hi);
      }
      ftab[e] = v;
    }
  }
}

// ---------- main: one wave per (bp, t-tile); 24576 waves; atomic combine ----------
__global__ __launch_bounds__(256, 4)
void fused_t(const float* __restrict__ expansion,
             const float* __restrict__ mask,
             const float* __restrict__ edge_dist,
             const float* __restrict__ b1e,
             const float* __restrict__ b2e,
             const float* __restrict__ b2n,
             const float* __restrict__ src_ws,
             const float* __restrict__ tgt_ws,
             const int4* __restrict__ ftab,
             float* __restrict__ out)
{
  const int tid  = threadIdx.x;
  const int wid  = tid >> 6;
  const int lane = tid & 63;
  const int col  = lane & 31;    // matrix column (= a within tile)
  const int hw   = lane >> 5;    // half-wave (k-split)

  __shared__ __align__(16) float smb[96];   // b1e | b2e | b2n
  if (tid < 32) {
    smb[tid]      = b1e[tid];
    smb[32 + tid] = b2e[tid];
    smb[64 + tid] = b2n[tid];
  }
  __syncthreads();

  const unsigned w  = blockIdx.x * 4 + wid;   // 0 .. 24575
  const unsigned bp = w / 3u;
  const int      t  = (int)(w - 3u * bp);
  const int      b  = (int)(bp >> 12);        // NP = 4096
  const int      a  = t * 32 + col;

  // ---- GEMM1: H1^T[j][a] = b1e[j] + sum_e W1e[e][j] * exp[bp][a][e] ----
  const float* ea = expansion + (size_t)bp * (NA * NE) + a * NE;
  float4 e0 = *reinterpret_cast<const float4*>(ea + 8 * hw);
  float4 e1 = *reinterpret_cast<const float4*>(ea + 8 * hw + 4);
  float4 e2 = *reinterpret_cast<const float4*>(ea + 16);   // e=16..19 (hw0 uses)
  Frag b1f0, b1f1;
  b1f0.i[0] = cvtpk(e0.x, e0.y);
  b1f0.i[1] = cvtpk(e0.z, e0.w);
  b1f0.i[2] = cvtpk(e1.x, e1.y);
  b1f0.i[3] = cvtpk(e1.z, e1.w);
  b1f1.i[0] = hw ? 0 : cvtpk(e2.x, e2.y);
  b1f1.i[1] = hw ? 0 : cvtpk(e2.z, e2.w);
  b1f1.i[2] = 0;
  b1f1.i[3] = 0;

  Frag aw;
  f32x16 d1 = ld_bias16(smb + 4 * hw);
  { int4 q = ftab[0 * 64 + lane]; aw.i[0]=q.x; aw.i[1]=q.y; aw.i[2]=q.z; aw.i[3]=q.w; }
  d1 = mfma32(aw, b1f0, d1);
  { int4 q = ftab[1 * 64 + lane]; aw.i[0]=q.x; aw.i[1]=q.y; aw.i[2]=q.z; aw.i[3]=q.w; }
  d1 = mfma32(aw, b1f1, d1);
#pragma unroll
  for (int r = 0; r < 16; ++r) d1[r] = ssp_f(d1[r]);

  // ---- C-layout f32 -> B-layout bf16 (cvt_pk + permlane32_swap) ----
  int u0 = cvtpk(d1[0],  d1[1]);
  int u1 = cvtpk(d1[2],  d1[3]);
  int u2 = cvtpk(d1[4],  d1[5]);
  int u3 = cvtpk(d1[6],  d1[7]);
  int u4 = cvtpk(d1[8],  d1[9]);
  int u5 = cvtpk(d1[10], d1[11]);
  int u6 = cvtpk(d1[12], d1[13]);
  int u7 = cvtpk(d1[14], d1[15]);
  asm("v_permlane32_swap_b32 %0, %1" : "+v"(u0), "+v"(u2));
  asm("v_permlane32_swap_b32 %0, %1" : "+v"(u1), "+v"(u3));
  asm("v_permlane32_swap_b32 %0, %1" : "+v"(u4), "+v"(u6));
  asm("v_permlane32_swap_b32 %0, %1" : "+v"(u5), "+v"(u7));
  Frag b2f0, b2f1;
  b2f0.i[0] = u0; b2f0.i[1] = u1; b2f0.i[2] = u2; b2f0.i[3] = u3;
  b2f1.i[0] = u4; b2f1.i[1] = u5; b2f1.i[2] = u6; b2f1.i[3] = u7;

  // ---- GEMM2: gates^T[f][a] ----
  f32x16 d2 = ld_bias16(smb + 32 + 4 * hw);
  { int4 q = ftab[2 * 64 + lane]; aw.i[0]=q.x; aw.i[1]=q.y; aw.i[2]=q.z; aw.i[3]=q.w; }
  d2 = mfma32(aw, b2f0, d2);
  { int4 q = ftab[3 * 64 + lane]; aw.i[0]=q.x; aw.i[1]=q.y; aw.i[2]=q.z; aw.i[3]=q.w; }
  d2 = mfma32(aw, b2f1, d2);

  // mask * cutoff envelope: mk / (1 + exp(5*(d-3.5)))
  const float mk = mask[bp * NA + a];
  const float dd = edge_dist[bp * NA + a];
  const float z  = __expf(5.0f * (dd - 3.5f));
  const float em = mk * __builtin_amdgcn_rcpf(1.0f + z);

  // ---- nodes B-fragment: ssp(src[b][a][fh] + tgt[bp][fh]) ----
  const float* sa = src_ws + (b * NA + a) * NF;
  const float* tg = tgt_ws + bp * NF;
  float4 s0 = *reinterpret_cast<const float4*>(sa + 8 * hw);
  float4 s1 = *reinterpret_cast<const float4*>(sa + 8 * hw + 4);
  float4 s2 = *reinterpret_cast<const float4*>(sa + 16 + 8 * hw);
  float4 s3 = *reinterpret_cast<const float4*>(sa + 16 + 8 * hw + 4);
  float4 t0 = *reinterpret_cast<const float4*>(tg + 8 * hw);
  float4 t1 = *reinterpret_cast<const float4*>(tg + 8 * hw + 4);
  float4 t2 = *reinterpret_cast<const float4*>(tg + 16 + 8 * hw);
  float4 t3 = *reinterpret_cast<const float4*>(tg + 16 + 8 * hw + 4);
  Frag b3f0, b3f1;
  b3f0.i[0] = cvtpk(ssp_f(s0.x + t0.x), ssp_f(s0.y + t0.y));
  b3f0.i[1] = cvtpk(ssp_f(s0.z + t0.z), ssp_f(s0.w + t0.w));
  b3f0.i[2] = cvtpk(ssp_f(s1.x + t1.x), ssp_f(s1.y + t1.y));
  b3f0.i[3] = cvtpk(ssp_f(s1.z + t1.z), ssp_f(s1.w + t1.w));
  b3f1.i[0] = cvtpk(ssp_f(s2.x + t2.x), ssp_f(s2.y + t2.y));
  b3f1.i[1] = cvtpk(ssp_f(s2.z + t2.z), ssp_f(s2.w + t2.w));
  b3f1.i[2] = cvtpk(ssp_f(s3.x + t3.x), ssp_f(s3.y + t3.y));
  b3f1.i[3] = cvtpk(ssp_f(s3.z + t3.z), ssp_f(s3.w + t3.w));

  // ---- GEMM3: nodes^T[fo][a] ----
  f32x16 d3 = ld_bias16(smb + 64 + 4 * hw);
  { int4 q = ftab[4 * 64 + lane]; aw.i[0]=q.x; aw.i[1]=q.y; aw.i[2]=q.z; aw.i[3]=q.w; }
  d3 = mfma32(aw, b3f0, d3);
  { int4 q = ftab[5 * 64 + lane]; aw.i[0]=q.x; aw.i[1]=q.y; aw.i[2]=q.z; aw.i[3]=q.w; }
  d3 = mfma32(aw, b3f1, d3);

  // ---- partial = em * gates ⊙ nodes; reduce over 32 cols; atomic combine ----
#pragma unroll
  for (int r = 0; r < 16; ++r) d3[r] = em * d2[r] * d3[r];

#pragma unroll
  for (int m = 1; m <= 16; m <<= 1) {
#pragma unroll
    for (int r = 0; r < 16; ++r) d3[r] += __shfl_xor(d3[r], m, 64);
  }

  if (col == 0) {
    float* o = out + bp * NF + 4 * hw;
#pragma unroll
    for (int r = 0; r < 16; ++r)
      atomicAdd(o + ((r & 3) + 8 * (r >> 2)), d3[r]);
  }
}

extern "C" void kernel_launch(void* const* d_in, const int* in_sizes, int n_in,
                              void* d_out, int out_size, void* d_ws, size_t ws_size,
                              hipStream_t stream) {
  const float* scalar    = (const float*)d_in[0];
  const float* sreciever = (const float*)d_in[1];
  const float* expansion = (const float*)d_in[2];
  const float* maskp     = (const float*)d_in[3];
  const float* edist     = (const float*)d_in[4];
  const float* W1e       = (const float*)d_in[5];
  const float* b1e       = (const float*)d_in[6];
  const float* W2e       = (const float*)d_in[7];
  const float* b2e       = (const float*)d_in[8];
  const float* W1n       = (const float*)d_in[9];
  const float* b1n       = (const float*)d_in[10];
  const float* W2n       = (const float*)d_in[11];
  const float* b2n       = (const float*)d_in[12];
  float* out    = (float*)d_out;
  float* src_ws = (float*)d_ws;                              // 192*32 f32 = 24576 B
  int4*  ftab   = (int4*)((char*)d_ws + 24576);              // 384 int4  =  6144 B
  float* tgt_ws = (float*)((char*)d_ws + 24576 + 6144);      // 8192*32 f32 = 1 MB

  hipMemsetAsync(out, 0, (size_t)out_size * sizeof(float), stream);
  prep_kernel<<<1050, 256, 0, stream>>>(scalar, sreciever, W1e, W2e, W2n,
                                        W1n, b1n, tgt_ws, src_ws, ftab);
  // 8192 bp * 3 tiles = 24576 waves = 6144 blocks of 4 waves
  fused_t<<<6144, 256, 0, stream>>>(expansion, maskp, edist,
                                    b1e, b2e, b2n, src_ws, tgt_ws, ftab, out);
}

// Round 7
// 149.642 us; speedup vs baseline: 1.0599x; 1.0241x over previous
//
#include <hip/hip_runtime.h>

// DeepDFTinv message block: B=2, P=4096, A=96, G=1, F=32, E=20
#define NB   2
#define NP   4096
#define NA   96
#define NF   32
#define NE   20
#define NBP  (NB*NP)

typedef __attribute__((ext_vector_type(8)))  short bf16x8;   // MFMA A/B frag (4 VGPRs)
typedef __attribute__((ext_vector_type(16))) float f32x16;   // 32x32 MFMA C/D frag

union Frag { bf16x8 v; int i[4]; };

// single-instruction packed f32->bf16 (RNE), src0 -> low half
__device__ __forceinline__ int cvtpk(float lo, float hi) {
  int r;
  asm("v_cvt_pk_bf16_f32 %0, %1, %2" : "=v"(r) : "v"(lo), "v"(hi));
  return r;
}
// shifted softplus: max(x,0) + log(1 + exp(-|x|)) - ln2
__device__ __forceinline__ float ssp_f(float x) {
  float t = __expf(-fabsf(x));
  return fmaxf(x, 0.0f) + __logf(1.0f + t) - 0.69314718056f;
}
__device__ __forceinline__ f32x16 mfma32(const Frag a, const Frag b, f32x16 c) {
  return __builtin_amdgcn_mfma_f32_32x32x16_bf16(a.v, b.v, c, 0, 0, 0);
}
// C-init from 32-float bias vector (global, L1-hot). rows = (r&3)+8*(r>>2)+4*hw
__device__ __forceinline__ f32x16 ld_bias16(const float* __restrict__ base /* bias + 4*hw */) {
  const float4* p = reinterpret_cast<const float4*>(base);
  float4 q0 = p[0], q1 = p[2], q2 = p[4], q3 = p[6];
  f32x16 c;
  c[0]=q0.x;  c[1]=q0.y;  c[2]=q0.z;  c[3]=q0.w;
  c[4]=q1.x;  c[5]=q1.y;  c[6]=q1.z;  c[7]=q1.w;
  c[8]=q2.x;  c[9]=q2.y;  c[10]=q2.z; c[11]=q2.w;
  c[12]=q3.x; c[13]=q3.y; c[14]=q3.z; c[15]=q3.w;
  return c;
}

// ---------- prep ----------
// blocks [0,1048): tgt = sr @ Wt -> tgt_ws; src = scalar @ Ws + b1n -> src_ws
// blocks [1048,1050): pack the 6 transposed bf16 weight fragments -> ftab
__global__ __launch_bounds__(256)
void prep_kernel(const float* __restrict__ scalar,
                 const float* __restrict__ sr,
                 const float* __restrict__ W1e,
                 const float* __restrict__ W2e,
                 const float* __restrict__ W2n,
                 const float* __restrict__ W1n,
                 const float* __restrict__ b1n,
                 float* __restrict__ tgt_ws,
                 float* __restrict__ src_ws,
                 int4* __restrict__ ftab)
{
  const int blk = blockIdx.x;
  if (blk < 1048) {
    int i = blk * 256 + threadIdx.x;     // 1048*256 = (8192+192)*32 exactly
    int f   = i & 31;
    int row = i >> 5;
    const float* x;
    const float* W;
    float acc;
    if (row < NBP) { x = sr + row * NF;             W = W1n + NF * NF; acc = 0.0f;   }
    else           { x = scalar + (row - NBP) * NF; W = W1n;           acc = b1n[f]; }
    float4 xv[8];
#pragma unroll
    for (int q = 0; q < 8; ++q) xv[q] = reinterpret_cast<const float4*>(x)[q];
#pragma unroll
    for (int q = 0; q < 8; ++q) {
      acc = fmaf(xv[q].x, W[(4 * q + 0) * NF + f], acc);
      acc = fmaf(xv[q].y, W[(4 * q + 1) * NF + f], acc);
      acc = fmaf(xv[q].z, W[(4 * q + 2) * NF + f], acc);
      acc = fmaf(xv[q].w, W[(4 * q + 3) * NF + f], acc);
    }
    if (row < NBP) tgt_ws[i] = acc;
    else           src_ws[(row - NBP) * NF + f] = acc;
  } else {
    int e = (blk - 1048) * 256 + threadIdx.x;   // 0..383 valid
    if (e < 384) {
      const int f  = e >> 6;        // frag id: 0..5
      const int l  = e & 63;
      const int c  = l & 31;
      const int hw = l >> 5;
      const float* W = (f < 2) ? W1e : ((f < 4) ? W2e : W2n);
      const int kbase = (f & 1) ? (16 + 8 * hw) : (8 * hw);
      int4 v;
      int* vi = reinterpret_cast<int*>(&v);
#pragma unroll
      for (int r = 0; r < 4; ++r) {
        int ka = kbase + 2 * r, kb = ka + 1;
        bool pa = (f == 1) && (ka >= NE);     // zero-pad e>=20 in W1e^T high-K frag
        bool pb = (f == 1) && (kb >= NE);
        float lo = W[(pa ? 0 : ka) * NF + c]; lo = pa ? 0.0f : lo;
        float hi = W[(pb ? 0 : kb) * NF + c]; hi = pb ? 0.0f : hi;
        vi[r] = cvtpk(lo, hi);
      }
      ftab[e] = v;
    }
  }
}

// ---------- main: one wave per (bp, t-tile); a-reduction via MFMA; atomic combine ----------
__global__ __launch_bounds__(256, 4)
void fused_t(const float* __restrict__ expansion,
             const float* __restrict__ mask,
             const float* __restrict__ edge_dist,
             const float* __restrict__ b1e,
             const float* __restrict__ b2e,
             const float* __restrict__ b2n,
             const float* __restrict__ src_ws,
             const float* __restrict__ tgt_ws,
             const int4* __restrict__ ftab,
             float* __restrict__ out)
{
  const int tid  = threadIdx.x;
  const int wid  = tid >> 6;
  const int lane = tid & 63;
  const int col  = lane & 31;    // lane-dim index
  const int hw   = lane >> 5;    // half-wave (k-split)

  const unsigned w  = blockIdx.x * 4 + wid;   // 0 .. 24575
  const unsigned bp = w / 3u;
  const int      t  = (int)(w - 3u * bp);
  const int      b  = (int)(bp >> 12);        // NP = 4096
  const int      a  = t * 32 + col;

  // ---- GEMM1 (transposed): H1^T[j][a] = b1e[j] + sum_e W1e[e][j] * exp[bp][a][e] ----
  const float* ea = expansion + (size_t)bp * (NA * NE) + a * NE;
  float4 e0 = *reinterpret_cast<const float4*>(ea + 8 * hw);
  float4 e1 = *reinterpret_cast<const float4*>(ea + 8 * hw + 4);
  float4 e2 = *reinterpret_cast<const float4*>(ea + 16);   // e=16..19 (hw0 uses)
  Frag b1f0, b1f1;
  b1f0.i[0] = cvtpk(e0.x, e0.y);
  b1f0.i[1] = cvtpk(e0.z, e0.w);
  b1f0.i[2] = cvtpk(e1.x, e1.y);
  b1f0.i[3] = cvtpk(e1.z, e1.w);
  b1f1.i[0] = hw ? 0 : cvtpk(e2.x, e2.y);
  b1f1.i[1] = hw ? 0 : cvtpk(e2.z, e2.w);
  b1f1.i[2] = 0;
  b1f1.i[3] = 0;

  Frag aw;
  f32x16 d1 = ld_bias16(b1e + 4 * hw);
  { int4 q = ftab[0 * 64 + lane]; aw.i[0]=q.x; aw.i[1]=q.y; aw.i[2]=q.z; aw.i[3]=q.w; }
  d1 = mfma32(aw, b1f0, d1);
  { int4 q = ftab[1 * 64 + lane]; aw.i[0]=q.x; aw.i[1]=q.y; aw.i[2]=q.z; aw.i[3]=q.w; }
  d1 = mfma32(aw, b1f1, d1);
#pragma unroll
  for (int r = 0; r < 16; ++r) d1[r] = ssp_f(d1[r]);

  // ---- C-layout (row=j, col=a) -> frag with k=j, n/m=a (cvt_pk + permlane32_swap) ----
  int u0 = cvtpk(d1[0],  d1[1]);
  int u1 = cvtpk(d1[2],  d1[3]);
  int u2 = cvtpk(d1[4],  d1[5]);
  int u3 = cvtpk(d1[6],  d1[7]);
  int u4 = cvtpk(d1[8],  d1[9]);
  int u5 = cvtpk(d1[10], d1[11]);
  int u6 = cvtpk(d1[12], d1[13]);
  int u7 = cvtpk(d1[14], d1[15]);
  asm("v_permlane32_swap_b32 %0, %1" : "+v"(u0), "+v"(u2));
  asm("v_permlane32_swap_b32 %0, %1" : "+v"(u1), "+v"(u3));
  asm("v_permlane32_swap_b32 %0, %1" : "+v"(u4), "+v"(u6));
  asm("v_permlane32_swap_b32 %0, %1" : "+v"(u5), "+v"(u7));
  Frag b2f0, b2f1;
  b2f0.i[0] = u0; b2f0.i[1] = u1; b2f0.i[2] = u2; b2f0.i[3] = u3;
  b2f1.i[0] = u4; b2f1.i[1] = u5; b2f1.i[2] = u6; b2f1.i[3] = u7;

  // ---- GEMM2' (non-transposed): gates'[a][f] = b2e[f] + sum_j sspE[j][a] W2e[j][f]
  //      A = b2f (same data, A-frag view: m=a, k=j); B = ftab W2e frags ----
  const float be = b2e[col];
  f32x16 d2;
#pragma unroll
  for (int r = 0; r < 16; ++r) d2[r] = be;
  { int4 q = ftab[2 * 64 + lane]; aw.i[0]=q.x; aw.i[1]=q.y; aw.i[2]=q.z; aw.i[3]=q.w; }
  d2 = mfma32(b2f0, aw, d2);
  { int4 q = ftab[3 * 64 + lane]; aw.i[0]=q.x; aw.i[1]=q.y; aw.i[2]=q.z; aw.i[3]=q.w; }
  d2 = mfma32(b2f1, aw, d2);

  // mask * cutoff envelope: mk / (1 + exp(5*(d-3.5))) -- folded into nodes frag below
  const float mk = mask[bp * NA + a];
  const float dd = edge_dist[bp * NA + a];
  const float z  = __expf(5.0f * (dd - 3.5f));
  const float em = mk * __builtin_amdgcn_rcpf(1.0f + z);

  // ---- nodes A-fragment: em * ssp(src[b][a][fh] + tgt[bp][fh]) (m=a, k=fh) ----
  const float* sa = src_ws + (b * NA + a) * NF;
  const float* tg = tgt_ws + bp * NF;
  float4 s0 = *reinterpret_cast<const float4*>(sa + 8 * hw);
  float4 s1 = *reinterpret_cast<const float4*>(sa + 8 * hw + 4);
  float4 s2 = *reinterpret_cast<const float4*>(sa + 16 + 8 * hw);
  float4 s3 = *reinterpret_cast<const float4*>(sa + 16 + 8 * hw + 4);
  float4 t0 = *reinterpret_cast<const float4*>(tg + 8 * hw);
  float4 t1 = *reinterpret_cast<const float4*>(tg + 8 * hw + 4);
  float4 t2 = *reinterpret_cast<const float4*>(tg + 16 + 8 * hw);
  float4 t3 = *reinterpret_cast<const float4*>(tg + 16 + 8 * hw + 4);
  Frag b3f0, b3f1;
  b3f0.i[0] = cvtpk(em * ssp_f(s0.x + t0.x), em * ssp_f(s0.y + t0.y));
  b3f0.i[1] = cvtpk(em * ssp_f(s0.z + t0.z), em * ssp_f(s0.w + t0.w));
  b3f0.i[2] = cvtpk(em * ssp_f(s1.x + t1.x), em * ssp_f(s1.y + t1.y));
  b3f0.i[3] = cvtpk(em * ssp_f(s1.z + t1.z), em * ssp_f(s1.w + t1.w));
  b3f1.i[0] = cvtpk(em * ssp_f(s2.x + t2.x), em * ssp_f(s2.y + t2.y));
  b3f1.i[1] = cvtpk(em * ssp_f(s2.z + t2.z), em * ssp_f(s2.w + t2.w));
  b3f1.i[2] = cvtpk(em * ssp_f(s3.x + t3.x), em * ssp_f(s3.y + t3.y));
  b3f1.i[3] = cvtpk(em * ssp_f(s3.z + t3.z), em * ssp_f(s3.w + t3.w));

  // ---- GEMM3' (non-transposed): nodes'[a][fo] = b2n[fo] + sum_fh N[a][fh] W2n[fh][fo] ----
  const float bn = b2n[col];
  f32x16 d3;
#pragma unroll
  for (int r = 0; r < 16; ++r) d3[r] = bn;
  { int4 q = ftab[4 * 64 + lane]; aw.i[0]=q.x; aw.i[1]=q.y; aw.i[2]=q.z; aw.i[3]=q.w; }
  d3 = mfma32(b3f0, aw, d3);
  { int4 q = ftab[5 * 64 + lane]; aw.i[0]=q.x; aw.i[1]=q.y; aw.i[2]=q.z; aw.i[3]=q.w; }
  d3 = mfma32(b3f1, aw, d3);

  // ---- P[a][f] = gates' ⊙ nodes' (C-layout, row=a); convert -> B-frag (k=a, n=f) ----
  int p0 = cvtpk(d2[0]  * d3[0],  d2[1]  * d3[1]);
  int p1 = cvtpk(d2[2]  * d3[2],  d2[3]  * d3[3]);
  int p2 = cvtpk(d2[4]  * d3[4],  d2[5]  * d3[5]);
  int p3 = cvtpk(d2[6]  * d3[6],  d2[7]  * d3[7]);
  int p4 = cvtpk(d2[8]  * d3[8],  d2[9]  * d3[9]);
  int p5 = cvtpk(d2[10] * d3[10], d2[11] * d3[11]);
  int p6 = cvtpk(d2[12] * d3[12], d2[13] * d3[13]);
  int p7 = cvtpk(d2[14] * d3[14], d2[15] * d3[15]);
  asm("v_permlane32_swap_b32 %0, %1" : "+v"(p0), "+v"(p2));
  asm("v_permlane32_swap_b32 %0, %1" : "+v"(p1), "+v"(p3));
  asm("v_permlane32_swap_b32 %0, %1" : "+v"(p4), "+v"(p6));
  asm("v_permlane32_swap_b32 %0, %1" : "+v"(p5), "+v"(p7));
  Frag pb0, pb1;
  pb0.i[0] = p0; pb0.i[1] = p1; pb0.i[2] = p2; pb0.i[3] = p3;
  pb1.i[0] = p4; pb1.i[1] = p5; pb1.i[2] = p6; pb1.i[3] = p7;

  // ---- reduce over a via MFMA with A = ones: D[m][f] = sum_a P[a][f] ----
  Frag aones;
  aones.i[0] = 0x3F803F80; aones.i[1] = 0x3F803F80;
  aones.i[2] = 0x3F803F80; aones.i[3] = 0x3F803F80;
  f32x16 red;
#pragma unroll
  for (int r = 0; r < 16; ++r) red[r] = 0.0f;
  red = mfma32(aones, pb0, red);
  red = mfma32(aones, pb1, red);

  // every row of red holds the tile sum; one coalesced atomic per lane (hw0 half)
  if (lane < 32) atomicAdd(out + bp * NF + lane, red[0]);
}

extern "C" void kernel_launch(void* const* d_in, const int* in_sizes, int n_in,
                              void* d_out, int out_size, void* d_ws, size_t ws_size,
                              hipStream_t stream) {
  const float* scalar    = (const float*)d_in[0];
  const float* sreciever = (const float*)d_in[1];
  const float* expansion = (const float*)d_in[2];
  const float* maskp     = (const float*)d_in[3];
  const float* edist     = (const float*)d_in[4];
  const float* W1e       = (const float*)d_in[5];
  const float* b1e       = (const float*)d_in[6];
  const float* W2e       = (const float*)d_in[7];
  const float* b2e       = (const float*)d_in[8];
  const float* W1n       = (const float*)d_in[9];
  const float* b1n       = (const float*)d_in[10];
  const float* W2n       = (const float*)d_in[11];
  const float* b2n       = (const float*)d_in[12];
  float* out    = (float*)d_out;
  float* src_ws = (float*)d_ws;                              // 192*32 f32 = 24576 B
  int4*  ftab   = (int4*)((char*)d_ws + 24576);              // 384 int4  =  6144 B
  float* tgt_ws = (float*)((char*)d_ws + 24576 + 6144);      // 8192*32 f32 = 1 MB

  hipMemsetAsync(out, 0, (size_t)out_size * sizeof(float), stream);
  prep_kernel<<<1050, 256, 0, stream>>>(scalar, sreciever, W1e, W2e, W2n,
                                        W1n, b1n, tgt_ws, src_ws, ftab);
  // 8192 bp * 3 tiles = 24576 waves = 6144 blocks of 4 waves
  fused_t<<<6144, 256, 0, stream>>>(expansion, maskp, edist,
                                    b1e, b2e, b2n, src_ws, tgt_ws, ftab, out);
}

// Round 8
// 145.772 us; speedup vs baseline: 1.0880x; 1.0265x over previous
//
#include <hip/hip_runtime.h>

// DeepDFTinv message block: B=2, P=4096, A=96, G=1, F=32, E=20
#define NB   2
#define NP   4096
#define NA   96
#define NF   32
#define NE   20
#define NBP  (NB*NP)

typedef __attribute__((ext_vector_type(8)))  short bf16x8;   // MFMA A/B frag (4 VGPRs)
typedef __attribute__((ext_vector_type(16))) float f32x16;   // 32x32 MFMA C/D frag

union Frag { bf16x8 v; int i[4]; };

// single-instruction packed f32->bf16 (RNE), src0 -> low half
__device__ __forceinline__ int cvtpk(float lo, float hi) {
  int r;
  asm("v_cvt_pk_bf16_f32 %0, %1, %2" : "=v"(r) : "v"(lo), "v"(hi));
  return r;
}
// shifted softplus: max(x,0) + log(1 + exp(-|x|)) - ln2
__device__ __forceinline__ float ssp_f(float x) {
  float t = __expf(-fabsf(x));
  return fmaxf(x, 0.0f) + __logf(1.0f + t) - 0.69314718056f;
}
__device__ __forceinline__ f32x16 mfma32(const Frag a, const Frag b, f32x16 c) {
  return __builtin_amdgcn_mfma_f32_32x32x16_bf16(a.v, b.v, c, 0, 0, 0);
}
// C-init from 32-float bias vector (global, L1-hot). rows = (r&3)+8*(r>>2)+4*hw
__device__ __forceinline__ f32x16 ld_bias16(const float* __restrict__ base /* bias + 4*hw */) {
  const float4* p = reinterpret_cast<const float4*>(base);
  float4 q0 = p[0], q1 = p[2], q2 = p[4], q3 = p[6];
  f32x16 c;
  c[0]=q0.x;  c[1]=q0.y;  c[2]=q0.z;  c[3]=q0.w;
  c[4]=q1.x;  c[5]=q1.y;  c[6]=q1.z;  c[7]=q1.w;
  c[8]=q2.x;  c[9]=q2.y;  c[10]=q2.z; c[11]=q2.w;
  c[12]=q3.x; c[13]=q3.y; c[14]=q3.z; c[15]=q3.w;
  return c;
}
__device__ __forceinline__ Frag ld_frag(const int4* __restrict__ p) {
  int4 q = *p;
  Frag f; f.i[0] = q.x; f.i[1] = q.y; f.i[2] = q.z; f.i[3] = q.w;
  return f;
}

// ---------- prep ----------
// blocks [0,1048): tgt = sr @ Wt -> tgt_ws; src = scalar @ Ws + b1n -> src_ws
// blocks [1048,1050): pack the 6 transposed bf16 weight fragments -> ftab
__global__ __launch_bounds__(256)
void prep_kernel(const float* __restrict__ scalar,
                 const float* __restrict__ sr,
                 const float* __restrict__ W1e,
                 const float* __restrict__ W2e,
                 const float* __restrict__ W2n,
                 const float* __restrict__ W1n,
                 const float* __restrict__ b1n,
                 float* __restrict__ tgt_ws,
                 float* __restrict__ src_ws,
                 int4* __restrict__ ftab)
{
  const int blk = blockIdx.x;
  if (blk < 1048) {
    int i = blk * 256 + threadIdx.x;     // 1048*256 = (8192+192)*32 exactly
    int f   = i & 31;
    int row = i >> 5;
    const float* x;
    const float* W;
    float acc;
    if (row < NBP) { x = sr + row * NF;             W = W1n + NF * NF; acc = 0.0f;   }
    else           { x = scalar + (row - NBP) * NF; W = W1n;           acc = b1n[f]; }
    float4 xv[8];
#pragma unroll
    for (int q = 0; q < 8; ++q) xv[q] = reinterpret_cast<const float4*>(x)[q];
#pragma unroll
    for (int q = 0; q < 8; ++q) {
      acc = fmaf(xv[q].x, W[(4 * q + 0) * NF + f], acc);
      acc = fmaf(xv[q].y, W[(4 * q + 1) * NF + f], acc);
      acc = fmaf(xv[q].z, W[(4 * q + 2) * NF + f], acc);
      acc = fmaf(xv[q].w, W[(4 * q + 3) * NF + f], acc);
    }
    if (row < NBP) tgt_ws[i] = acc;
    else           src_ws[(row - NBP) * NF + f] = acc;
  } else {
    int e = (blk - 1048) * 256 + threadIdx.x;   // 0..383 valid
    if (e < 384) {
      const int f  = e >> 6;        // frag id: 0..5
      const int l  = e & 63;
      const int c  = l & 31;
      const int hw = l >> 5;
      const float* W = (f < 2) ? W1e : ((f < 4) ? W2e : W2n);
      const int kbase = (f & 1) ? (16 + 8 * hw) : (8 * hw);
      int4 v;
      int* vi = reinterpret_cast<int*>(&v);
#pragma unroll
      for (int r = 0; r < 4; ++r) {
        int ka = kbase + 2 * r, kb = ka + 1;
        bool pa = (f == 1) && (ka >= NE);     // zero-pad e>=20 in W1e^T high-K frag
        bool pb = (f == 1) && (kb >= NE);
        float lo = W[(pa ? 0 : ka) * NF + c]; lo = pa ? 0.0f : lo;
        float hi = W[(pb ? 0 : kb) * NF + c]; hi = pb ? 0.0f : hi;
        vi[r] = cvtpk(lo, hi);
      }
      ftab[e] = v;
    }
  }
}

// ---------- main: one wave per (bp, t-tile); a-reduction via MFMA; atomic combine ----------
__global__ __launch_bounds__(256, 4)
void fused_t(const float* __restrict__ expansion,
             const float* __restrict__ mask,
             const float* __restrict__ edge_dist,
             const float* __restrict__ b1e,
             const float* __restrict__ b2e,
             const float* __restrict__ b2n,
             const float* __restrict__ src_ws,
             const float* __restrict__ tgt_ws,
             const int4* __restrict__ ftab,
             float* __restrict__ out)
{
  const int tid  = threadIdx.x;
  const int wid  = tid >> 6;
  const int lane = tid & 63;
  const int col  = lane & 31;    // lane-dim index
  const int hw   = lane >> 5;    // half-wave (k-split)

  const unsigned w  = blockIdx.x * 4 + wid;   // 0 .. 24575
  const unsigned bp = w / 3u;
  const int      t  = (int)(w - 3u * bp);
  const int      b  = (int)(bp >> 12);        // NP = 4096
  const int      a  = t * 32 + col;

  // ======== PROLOGUE: issue all weight-frag / scalar loads up front ========
  Frag aw1a = ld_frag(ftab + 0 * 64 + lane);
  Frag aw1b = ld_frag(ftab + 1 * 64 + lane);
  Frag aw2a = ld_frag(ftab + 2 * 64 + lane);
  Frag aw2b = ld_frag(ftab + 3 * 64 + lane);
  Frag aw3a = ld_frag(ftab + 4 * 64 + lane);
  Frag aw3b = ld_frag(ftab + 5 * 64 + lane);
  const float mk = mask[bp * NA + a];
  const float dd = edge_dist[bp * NA + a];
  const float be = b2e[col];
  const float bn = b2n[col];

  // ---- expansion fragment loads ----
  const float* ea = expansion + (size_t)bp * (NA * NE) + a * NE;
  float4 e0 = *reinterpret_cast<const float4*>(ea + 8 * hw);
  float4 e1 = *reinterpret_cast<const float4*>(ea + 8 * hw + 4);
  float4 e2 = *reinterpret_cast<const float4*>(ea + 16);   // e=16..19 (hw0 uses)

  // mask * cutoff envelope, computed early (fills load-wait / MFMA shadow)
  const float z  = __expf(5.0f * (dd - 3.5f));
  const float em = mk * __builtin_amdgcn_rcpf(1.0f + z);

  Frag b1f0, b1f1;
  b1f0.i[0] = cvtpk(e0.x, e0.y);
  b1f0.i[1] = cvtpk(e0.z, e0.w);
  b1f0.i[2] = cvtpk(e1.x, e1.y);
  b1f0.i[3] = cvtpk(e1.z, e1.w);
  b1f1.i[0] = hw ? 0 : cvtpk(e2.x, e2.y);
  b1f1.i[1] = hw ? 0 : cvtpk(e2.z, e2.w);
  b1f1.i[2] = 0;
  b1f1.i[3] = 0;

  // ---- GEMM1 (transposed): H1^T[j][a] = b1e[j] + sum_e W1e[e][j] * exp[bp][a][e] ----
  f32x16 d1 = ld_bias16(b1e + 4 * hw);
  d1 = mfma32(aw1a, b1f0, d1);
  d1 = mfma32(aw1b, b1f1, d1);
#pragma unroll
  for (int r = 0; r < 16; ++r) d1[r] = ssp_f(d1[r]);

  // ---- C-layout (row=j, col=a) -> frag with k=j, n/m=a (cvt_pk + permlane32_swap) ----
  int u0 = cvtpk(d1[0],  d1[1]);
  int u1 = cvtpk(d1[2],  d1[3]);
  int u2 = cvtpk(d1[4],  d1[5]);
  int u3 = cvtpk(d1[6],  d1[7]);
  int u4 = cvtpk(d1[8],  d1[9]);
  int u5 = cvtpk(d1[10], d1[11]);
  int u6 = cvtpk(d1[12], d1[13]);
  int u7 = cvtpk(d1[14], d1[15]);
  asm("v_permlane32_swap_b32 %0, %1" : "+v"(u0), "+v"(u2));
  asm("v_permlane32_swap_b32 %0, %1" : "+v"(u1), "+v"(u3));
  asm("v_permlane32_swap_b32 %0, %1" : "+v"(u4), "+v"(u6));
  asm("v_permlane32_swap_b32 %0, %1" : "+v"(u5), "+v"(u7));
  Frag b2f0, b2f1;
  b2f0.i[0] = u0; b2f0.i[1] = u1; b2f0.i[2] = u2; b2f0.i[3] = u3;
  b2f1.i[0] = u4; b2f1.i[1] = u5; b2f1.i[2] = u6; b2f1.i[3] = u7;

  // ---- GEMM2' (non-transposed): gates'[a][f] = b2e[f] + sum_j sspE[j][a] W2e[j][f] ----
  f32x16 d2;
#pragma unroll
  for (int r = 0; r < 16; ++r) d2[r] = be;
  d2 = mfma32(b2f0, aw2a, d2);
  d2 = mfma32(b2f1, aw2b, d2);

  // ---- nodes A-fragment: em * ssp(src[b][a][fh] + tgt[bp][fh]) (m=a, k=fh) ----
  const float* sa = src_ws + (b * NA + a) * NF;
  const float* tg = tgt_ws + bp * NF;
  float4 s0 = *reinterpret_cast<const float4*>(sa + 8 * hw);
  float4 s1 = *reinterpret_cast<const float4*>(sa + 8 * hw + 4);
  float4 s2 = *reinterpret_cast<const float4*>(sa + 16 + 8 * hw);
  float4 s3 = *reinterpret_cast<const float4*>(sa + 16 + 8 * hw + 4);
  float4 t0 = *reinterpret_cast<const float4*>(tg + 8 * hw);
  float4 t1 = *reinterpret_cast<const float4*>(tg + 8 * hw + 4);
  float4 t2 = *reinterpret_cast<const float4*>(tg + 16 + 8 * hw);
  float4 t3 = *reinterpret_cast<const float4*>(tg + 16 + 8 * hw + 4);
  Frag b3f0, b3f1;
  b3f0.i[0] = cvtpk(em * ssp_f(s0.x + t0.x), em * ssp_f(s0.y + t0.y));
  b3f0.i[1] = cvtpk(em * ssp_f(s0.z + t0.z), em * ssp_f(s0.w + t0.w));
  b3f0.i[2] = cvtpk(em * ssp_f(s1.x + t1.x), em * ssp_f(s1.y + t1.y));
  b3f0.i[3] = cvtpk(em * ssp_f(s1.z + t1.z), em * ssp_f(s1.w + t1.w));
  b3f1.i[0] = cvtpk(em * ssp_f(s2.x + t2.x), em * ssp_f(s2.y + t2.y));
  b3f1.i[1] = cvtpk(em * ssp_f(s2.z + t2.z), em * ssp_f(s2.w + t2.w));
  b3f1.i[2] = cvtpk(em * ssp_f(s3.x + t3.x), em * ssp_f(s3.y + t3.y));
  b3f1.i[3] = cvtpk(em * ssp_f(s3.z + t3.z), em * ssp_f(s3.w + t3.w));

  // ---- GEMM3' (non-transposed): nodes'[a][fo] = b2n[fo] + sum_fh N[a][fh] W2n[fh][fo] ----
  f32x16 d3;
#pragma unroll
  for (int r = 0; r < 16; ++r) d3[r] = bn;
  d3 = mfma32(b3f0, aw3a, d3);
  d3 = mfma32(b3f1, aw3b, d3);

  // ---- P[a][f] = gates' ⊙ nodes' (C-layout, row=a); convert -> B-frag (k=a, n=f) ----
  int p0 = cvtpk(d2[0]  * d3[0],  d2[1]  * d3[1]);
  int p1 = cvtpk(d2[2]  * d3[2],  d2[3]  * d3[3]);
  int p2 = cvtpk(d2[4]  * d3[4],  d2[5]  * d3[5]);
  int p3 = cvtpk(d2[6]  * d3[6],  d2[7]  * d3[7]);
  int p4 = cvtpk(d2[8]  * d3[8],  d2[9]  * d3[9]);
  int p5 = cvtpk(d2[10] * d3[10], d2[11] * d3[11]);
  int p6 = cvtpk(d2[12] * d3[12], d2[13] * d3[13]);
  int p7 = cvtpk(d2[14] * d3[14], d2[15] * d3[15]);
  asm("v_permlane32_swap_b32 %0, %1" : "+v"(p0), "+v"(p2));
  asm("v_permlane32_swap_b32 %0, %1" : "+v"(p1), "+v"(p3));
  asm("v_permlane32_swap_b32 %0, %1" : "+v"(p4), "+v"(p6));
  asm("v_permlane32_swap_b32 %0, %1" : "+v"(p5), "+v"(p7));
  Frag pb0, pb1;
  pb0.i[0] = p0; pb0.i[1] = p1; pb0.i[2] = p2; pb0.i[3] = p3;
  pb1.i[0] = p4; pb1.i[1] = p5; pb1.i[2] = p6; pb1.i[3] = p7;

  // ---- reduce over a via MFMA with A = ones: D[m][f] = sum_a P[a][f] ----
  Frag aones;
  aones.i[0] = 0x3F803F80; aones.i[1] = 0x3F803F80;
  aones.i[2] = 0x3F803F80; aones.i[3] = 0x3F803F80;
  f32x16 red;
#pragma unroll
  for (int r = 0; r < 16; ++r) red[r] = 0.0f;
  red = mfma32(aones, pb0, red);
  red = mfma32(aones, pb1, red);

  // every row of red holds the tile sum; one coalesced atomic per lane (hw0 half)
  if (lane < 32) atomicAdd(out + bp * NF + lane, red[0]);
}

extern "C" void kernel_launch(void* const* d_in, const int* in_sizes, int n_in,
                              void* d_out, int out_size, void* d_ws, size_t ws_size,
                              hipStream_t stream) {
  const float* scalar    = (const float*)d_in[0];
  const float* sreciever = (const float*)d_in[1];
  const float* expansion = (const float*)d_in[2];
  const float* maskp     = (const float*)d_in[3];
  const float* edist     = (const float*)d_in[4];
  const float* W1e       = (const float*)d_in[5];
  const float* b1e       = (const float*)d_in[6];
  const float* W2e       = (const float*)d_in[7];
  const float* b2e       = (const float*)d_in[8];
  const float* W1n       = (const float*)d_in[9];
  const float* b1n       = (const float*)d_in[10];
  const float* W2n       = (const float*)d_in[11];
  const float* b2n       = (const float*)d_in[12];
  float* out    = (float*)d_out;
  float* src_ws = (float*)d_ws;                              // 192*32 f32 = 24576 B
  int4*  ftab   = (int4*)((char*)d_ws + 24576);              // 384 int4  =  6144 B
  float* tgt_ws = (float*)((char*)d_ws + 24576 + 6144);      // 8192*32 f32 = 1 MB

  hipMemsetAsync(out, 0, (size_t)out_size * sizeof(float), stream);
  prep_kernel<<<1050, 256, 0, stream>>>(scalar, sreciever, W1e, W2e, W2n,
                                        W1n, b1n, tgt_ws, src_ws, ftab);
  // 8192 bp * 3 tiles = 24576 waves = 6144 blocks of 4 waves
  fused_t<<<6144, 256, 0, stream>>>(expansion, maskp, edist,
                                    b1e, b2e, b2n, src_ws, tgt_ws, ftab, out);
}